// Round 18
// baseline (266.130 us; speedup 1.0000x reference)
//
#include <hip/hip_runtime.h>

// LinOSS: damped-oscillator linear SSM scan. B=8, T=2048, H=16, D=64.
//   s = 1-sigmoid(osc_damp); a = DT*exp(osc_w)
//   z' = s*z - a*y + w,  w = DT*beta*k[d]*v[e];  y' = y + DT*z'
//   out = (1/8) q . y
//
// R17: occupancy axis closed (flat at 42% for arg2 in {4,5}); both passes
// scale with per-step instruction count -> issue-bound at fixed residency.
// R18: grid/residency fill. 1792-block grids = 1.75 resident waves -> 2
// phases, 2nd 75% full (~12% idle). Uneven 9 chunks: 0..7 len 224, chunk 8
// len 256. L1 = chunks 0..7 = 2048 blocks = 2 EXACT resident waves; L2 =
// chunks 1..8 = 2048 blocks at 224 steps (c8: 256). Prefix power A^224 =
// (A^7)^32 (A-live only in prologue). CL template keeps even-8 fallback.

constexpr float DTc = 0.01f;
constexpr int Tn = 2048, Hn = 16, Dn = 64;
constexpr int TS = Hn * Dn; // 1024 floats per t-step in q/k/v/out
constexpr int TILE = 16;

typedef const __attribute__((address_space(1))) void* as1_cvp;
typedef __attribute__((address_space(3))) void* as3_vp;

__device__ __forceinline__ void gload_lds4(const float* g, float* lds) {
    __builtin_amdgcn_global_load_lds((as1_cvp)g, (as3_vp)lds, 4, 0, 0);
}
__device__ __forceinline__ void gload_lds16(const float* g, float* lds) {
    __builtin_amdgcn_global_load_lds((as1_cvp)g, (as3_vp)lds, 16, 0, 0);
}

template<int CTRL>
__device__ __forceinline__ float dpp_add(float x) {
    int yi = __builtin_amdgcn_update_dpp(0, __float_as_int(x), CTRL, 0xF, 0xF, true);
    return x + __int_as_float(yi);
}

// CL = stored-chunk length (224 uneven-9 / 256 even-8). NST = stored chunks.
// MODE 0 (L1): c in [0,NST-1], len CL; c==0 direct+dot else eigen; store ws.
// MODE 1 (L2): c in [1,NST], len = (c==NST ? Tn-NST*CL : CL); prefix; dot.
template<int CL, int MODE>
__global__ __launch_bounds__(256, 4)
void linoss_k(const float* __restrict__ Q, const float* __restrict__ K,
              const float* __restrict__ V, const float* __restrict__ Bt,
              const float* __restrict__ OW, const float* __restrict__ OD,
              float* __restrict__ Out, float* __restrict__ WS) {
    constexpr int NST = (CL == 224) ? 8 : 7;

    __shared__ float sK[2][TILE][64];
    __shared__ float sQ[2][TILE][64];
    __shared__ float sV[2][TILE][32];
    __shared__ float sB[2][TILE];

    int blk = blockIdx.x;
    int c = (MODE == 0) ? (blk >> 8) : (1 + (blk >> 8));
    bool doQ = (MODE == 1) || (c == 0);
    int sl = blk & 255;
    // XCD-aware decode: both e-halves of the same (b,h) on one XCD.
    int xcd = sl & 7, slot = sl >> 3;
    int ec = slot & 1;
    int bh = ((slot >> 1) << 3) | xcd;
    int b = bh >> 4, h = bh & 15;

    int tid = threadIdx.x;
    int dgrp = tid & 7;
    int el = tid >> 3;
    int e = ec * 32 + el;
    int d0 = dgrp * 8;
    int wv = tid >> 6;
    int ln = tid & 63;

    float y[8], z[8];
#pragma unroll
    for (int j = 0; j < 8; ++j) { y[j] = 0.0f; z[j] = 0.0f; }

    auto wsBase = [&](int ci) {
        return WS + (((size_t)ci * 128 + bh) * 2 + ec) * 4096 + (size_t)tid * 16;
    };

    size_t bhOff = (size_t)b * Tn * TS + (size_t)h * Dn;
    const float* kb0 = K + bhOff;
    const float* qb0 = Q + bhOff;
    const float* vb0 = V + bhOff + ec * 32;
    const float* bb0 = Bt + (size_t)b * Tn * Hn + h;
    float* op = Out + bhOff + e;
    bool wlane = (dgrp == 0);

    int t0 = c * CL;
    int len = (MODE == 1 && c == NST) ? (Tn - NST * CL) : CL;
    int nT = len / TILE;

    auto stage = [&](int buf, int tt0) {
        {
            int row = 4 * wv + (ln >> 4);
            gload_lds16(kb0 + (size_t)(tt0 + row) * TS + (ln & 15) * 4, &sK[buf][4 * wv][0]);
        }
        if (doQ) {
            int row = 4 * wv + (ln >> 4);
            gload_lds16(qb0 + (size_t)(tt0 + row) * TS + (ln & 15) * 4, &sQ[buf][4 * wv][0]);
        }
        if (wv < 2) {
            int row = 8 * wv + (ln >> 3);
            gload_lds16(vb0 + (size_t)(tt0 + row) * TS + (ln & 7) * 4, &sV[buf][8 * wv][0]);
        }
        if (wv == 2 && ln < 16)
            gload_lds4(bb0 + (size_t)(tt0 + ln) * Hn, &sB[buf][0]);
    };

    if (MODE == 0 && c > 0) {
        // ---------------- eigen state-only sweep ----------------
        float l1[8], l2[8], mt1[8], mt2[8];
#pragma unroll
        for (int j = 0; j < 8; ++j) {
            int idx = (h * Dn + d0 + j) * Dn + e;
            float aDT = DTc * expf(OW[idx]);
            float s = 1.0f - 1.0f / (1.0f + expf(-OD[idx]));
            float a00 = 1.0f - DTc * aDT, a11 = s;
            float a01 = DTc * s, a10 = -aDT;
            float tr = a00 + a11;
            float dmm = a00 - a11;
            float disc = fmaf(dmm, dmm, 4.0f * a01 * a10);
            float sq = sqrtf(disc);
            l1[j] = 0.5f * (tr + sq);
            l2[j] = s / l1[j];        // det = s exactly
            mt1[j] = 0.0f; mt2[j] = 0.0f;
        }

        stage(0, t0);
        __syncthreads();
        for (int ti = 0; ti < nT; ++ti) {
            int cur = ti & 1;
            if (ti + 1 < nT) stage(cur ^ 1, t0 + (ti + 1) * TILE);
#pragma unroll 8
            for (int s = 0; s < TILE; ++s) {
                const float4* kr = (const float4*)&sK[cur][s][d0];
                float4 ka = kr[0], kb = kr[1];
                float vv = sV[cur][s][el];
                float bb = sB[cur][s];
                float bv = (DTc * bb) * vv;
                float kk[8] = {ka.x, ka.y, ka.z, ka.w, kb.x, kb.y, kb.z, kb.w};
#pragma unroll
                for (int j = 0; j < 8; ++j) {
                    float w = bv * kk[j];
                    mt1[j] = fmaf(l1[j], mt1[j], w);
                    mt2[j] = fmaf(l2[j], mt2[j], w);
                }
            }
            __syncthreads();
        }

#pragma unroll
        for (int j = 0; j < 8; ++j) {
            int idx = (h * Dn + d0 + j) * Dn + e;
            float aDT = DTc * expf(OW[idx]);
            float s = 1.0f - 1.0f / (1.0f + expf(-OD[idx]));
            float a00 = 1.0f - DTc * aDT, a11 = s;
            float a01 = DTc * s, a10 = -aDT;
            float b1 = a01 / (l1[j] - a11);
            float b2 = (l2[j] - a00) / a10;
            float c1 = DTc + b1, c2 = DTc + b2;
            float rdb = 1.0f / (b2 - b1);
            float Y1 = b2 * c1 * rdb, Y2 = -b1 * c2 * rdb;
            float Z1 = -c1 * rdb, Z2 = c2 * rdb;
            y[j] = fmaf(Y1, mt1[j], Y2 * mt2[j]);
            z[j] = fmaf(Z1, mt1[j], Z2 * mt2[j]);
        }
    } else {
        // ---------------- direct sweep (with dot) ----------------
        float aDT[8], omc[8];
#pragma unroll
        for (int j = 0; j < 8; ++j) {
            int idx = (h * Dn + d0 + j) * Dn + e;
            aDT[j] = DTc * expf(OW[idx]);
            omc[j] = 1.0f - 1.0f / (1.0f + expf(-OD[idx]));
        }

        if (MODE == 1 && c > 0) {
            // M = A^CL, then fold ws prefix states: s = M*s + c_i.
            float m00[8], m01[8], m10[8], m11[8];
            if constexpr (CL == 256) {
#pragma unroll
                for (int j = 0; j < 8; ++j) {
                    m00[j] = 1.0f - DTc * aDT[j];
                    m01[j] = DTc * omc[j];
                    m10[j] = -aDT[j];
                    m11[j] = omc[j];
                }
                for (int pw = 1; pw < CL; pw <<= 1) {
#pragma unroll
                    for (int j = 0; j < 8; ++j) {
                        float n00 = fmaf(m00[j], m00[j], m01[j] * m10[j]);
                        float n01 = fmaf(m00[j], m01[j], m01[j] * m11[j]);
                        float n10 = fmaf(m10[j], m00[j], m11[j] * m10[j]);
                        float n11 = fmaf(m10[j], m01[j], m11[j] * m11[j]);
                        m00[j] = n00; m01[j] = n01; m10[j] = n10; m11[j] = n11;
                    }
                }
            } else {
                // A^224 = (A^7)^32; A^7 = ((A^2 * A)^2) * A. A live only here.
#pragma unroll
                for (int j = 0; j < 8; ++j) {
                    float a00 = 1.0f - DTc * aDT[j];
                    float a01 = DTc * omc[j];
                    float a10 = -aDT[j];
                    float a11 = omc[j];
                    // m = A*A
                    float t00 = fmaf(a00, a00, a01 * a10);
                    float t01 = fmaf(a00, a01, a01 * a11);
                    float t10 = fmaf(a10, a00, a11 * a10);
                    float t11 = fmaf(a10, a01, a11 * a11);
                    // m = m*A  (A^3)
                    float u00 = fmaf(t00, a00, t01 * a10);
                    float u01 = fmaf(t00, a01, t01 * a11);
                    float u10 = fmaf(t10, a00, t11 * a10);
                    float u11 = fmaf(t10, a01, t11 * a11);
                    // m = m*m  (A^6)
                    t00 = fmaf(u00, u00, u01 * u10);
                    t01 = fmaf(u00, u01, u01 * u11);
                    t10 = fmaf(u10, u00, u11 * u10);
                    t11 = fmaf(u10, u01, u11 * u11);
                    // m = m*A  (A^7)
                    m00[j] = fmaf(t00, a00, t01 * a10);
                    m01[j] = fmaf(t00, a01, t01 * a11);
                    m10[j] = fmaf(t10, a00, t11 * a10);
                    m11[j] = fmaf(t10, a01, t11 * a11);
                }
                for (int sqi = 0; sqi < 5; ++sqi) {   // (A^7)^32
#pragma unroll
                    for (int j = 0; j < 8; ++j) {
                        float n00 = fmaf(m00[j], m00[j], m01[j] * m10[j]);
                        float n01 = fmaf(m00[j], m01[j], m01[j] * m11[j]);
                        float n10 = fmaf(m10[j], m00[j], m11[j] * m10[j]);
                        float n11 = fmaf(m10[j], m01[j], m11[j] * m11[j]);
                        m00[j] = n00; m01[j] = n01; m10[j] = n10; m11[j] = n11;
                    }
                }
            }
            for (int i = 0; i < c; ++i) {
                const float4* cw = (const float4*)wsBase(i);
                float4 w0 = cw[0], w1 = cw[1], w2 = cw[2], w3 = cw[3];
                float cy[8] = {w0.x, w0.z, w1.x, w1.z, w2.x, w2.z, w3.x, w3.z};
                float cz[8] = {w0.y, w0.w, w1.y, w1.w, w2.y, w2.w, w3.y, w3.w};
#pragma unroll
                for (int j = 0; j < 8; ++j) {
                    float ny = fmaf(m00[j], y[j], fmaf(m01[j], z[j], cy[j]));
                    float nz = fmaf(m10[j], y[j], fmaf(m11[j], z[j], cz[j]));
                    y[j] = ny; z[j] = nz;
                }
            }
        }

        stage(0, t0);
        __syncthreads();
        for (int ti = 0; ti < nT; ++ti) {
            int cur = ti & 1;
            if (ti + 1 < nT) stage(cur ^ 1, t0 + (ti + 1) * TILE);
            float* ops = op + (size_t)(t0 + ti * TILE) * TS;
#pragma unroll 8
            for (int s = 0; s < TILE; ++s) {
                const float4* kr = (const float4*)&sK[cur][s][d0];
                float4 ka = kr[0], kb = kr[1];
                float vv = sV[cur][s][el];
                float bb = sB[cur][s];
                float bv = (DTc * bb) * vv;
                float kk[8] = {ka.x, ka.y, ka.z, ka.w, kb.x, kb.y, kb.z, kb.w};
#pragma unroll
                for (int j = 0; j < 8; ++j) {
                    z[j] = fmaf(omc[j], z[j], fmaf(-aDT[j], y[j], bv * kk[j]));
                    y[j] = fmaf(DTc, z[j], y[j]);
                }
                {
                    const float4* qr = (const float4*)&sQ[cur][s][d0];
                    float4 qa = qr[0], qb = qr[1];
                    float qq[8] = {qa.x, qa.y, qa.z, qa.w, qb.x, qb.y, qb.z, qb.w};
                    float p = 0.0f;
#pragma unroll
                    for (int j = 0; j < 8; ++j) p = fmaf(qq[j], y[j], p);
                    p = dpp_add<0xB1>(p);
                    p = dpp_add<0x4E>(p);
                    p += __shfl_xor(p, 4);
                    if (wlane) *ops = p * 0.125f; // scale = D^-0.5
                    ops += TS;
                }
            }
            __syncthreads();
        }
    }

    if (MODE == 0) {
        float4* cw = (float4*)wsBase(c);
#pragma unroll
        for (int j = 0; j < 4; ++j) {
            float4 w;
            w.x = y[2 * j];     w.y = z[2 * j];
            w.z = y[2 * j + 1]; w.w = z[2 * j + 1];
            cw[j] = w;
        }
    }
}

// NC=1 full sequential fallback (tiny ws). Direct+dot over all T.
__global__ __launch_bounds__(256, 4)
void linoss_full(const float* __restrict__ Q, const float* __restrict__ K,
                 const float* __restrict__ V, const float* __restrict__ Bt,
                 const float* __restrict__ OW, const float* __restrict__ OD,
                 float* __restrict__ Out) {
    // reuse MODE1-style direct sweep with c fixed 0 via simple loop
    __shared__ float sK[2][TILE][64];
    __shared__ float sQ[2][TILE][64];
    __shared__ float sV[2][TILE][32];
    __shared__ float sB[2][TILE];
    int blk = blockIdx.x;
    int xcd = blk & 7, slot = blk >> 3;
    int ec = slot & 1;
    int bh = ((slot >> 1) << 3) | xcd;
    int b = bh >> 4, h = bh & 15;
    int tid = threadIdx.x;
    int dgrp = tid & 7, el = tid >> 3;
    int e = ec * 32 + el, d0 = dgrp * 8;
    int wv = tid >> 6, ln = tid & 63;
    float aDT[8], omc[8], y[8], z[8];
#pragma unroll
    for (int j = 0; j < 8; ++j) {
        int idx = (h * Dn + d0 + j) * Dn + e;
        aDT[j] = DTc * expf(OW[idx]);
        omc[j] = 1.0f - 1.0f / (1.0f + expf(-OD[idx]));
        y[j] = 0.0f; z[j] = 0.0f;
    }
    size_t bhOff = (size_t)b * Tn * TS + (size_t)h * Dn;
    const float* kb0 = K + bhOff;
    const float* qb0 = Q + bhOff;
    const float* vb0 = V + bhOff + ec * 32;
    const float* bb0 = Bt + (size_t)b * Tn * Hn + h;
    float* op = Out + bhOff + e;
    bool wlane = (dgrp == 0);
    auto stage = [&](int buf, int tt0) {
        { int row = 4 * wv + (ln >> 4);
          gload_lds16(kb0 + (size_t)(tt0 + row) * TS + (ln & 15) * 4, &sK[buf][4 * wv][0]); }
        { int row = 4 * wv + (ln >> 4);
          gload_lds16(qb0 + (size_t)(tt0 + row) * TS + (ln & 15) * 4, &sQ[buf][4 * wv][0]); }
        if (wv < 2) { int row = 8 * wv + (ln >> 3);
          gload_lds16(vb0 + (size_t)(tt0 + row) * TS + (ln & 7) * 4, &sV[buf][8 * wv][0]); }
        if (wv == 2 && ln < 16) gload_lds4(bb0 + (size_t)(tt0 + ln) * Hn, &sB[buf][0]);
    };
    stage(0, 0);
    __syncthreads();
    for (int ti = 0; ti < Tn / TILE; ++ti) {
        int cur = ti & 1;
        if (ti + 1 < Tn / TILE) stage(cur ^ 1, (ti + 1) * TILE);
        float* ops = op + (size_t)(ti * TILE) * TS;
#pragma unroll 8
        for (int s = 0; s < TILE; ++s) {
            const float4* kr = (const float4*)&sK[cur][s][d0];
            float4 ka = kr[0], kb = kr[1];
            float vv = sV[cur][s][el], bb = sB[cur][s];
            float bv = (DTc * bb) * vv;
            float kk[8] = {ka.x, ka.y, ka.z, ka.w, kb.x, kb.y, kb.z, kb.w};
#pragma unroll
            for (int j = 0; j < 8; ++j) {
                z[j] = fmaf(omc[j], z[j], fmaf(-aDT[j], y[j], bv * kk[j]));
                y[j] = fmaf(DTc, z[j], y[j]);
            }
            const float4* qr = (const float4*)&sQ[cur][s][d0];
            float4 qa = qr[0], qb = qr[1];
            float qq[8] = {qa.x, qa.y, qa.z, qa.w, qb.x, qb.y, qb.z, qb.w};
            float p = 0.0f;
#pragma unroll
            for (int j = 0; j < 8; ++j) p = fmaf(qq[j], y[j], p);
            p = dpp_add<0xB1>(p);
            p = dpp_add<0x4E>(p);
            p += __shfl_xor(p, 4);
            if (wlane) *ops = p * 0.125f;
            ops += TS;
        }
        __syncthreads();
    }
}

extern "C" void kernel_launch(void* const* d_in, const int* in_sizes, int n_in,
                              void* d_out, int out_size, void* d_ws, size_t ws_size,
                              hipStream_t stream) {
    const float* q  = (const float*)d_in[0];
    const float* k  = (const float*)d_in[1];
    const float* v  = (const float*)d_in[2];
    const float* bt = (const float*)d_in[3];
    const float* ow = (const float*)d_in[4];
    const float* od = (const float*)d_in[5];
    float* out = (float*)d_out;
    float* ws = (float*)d_ws;

    const size_t chunkBytes = (size_t)128 * 2 * 4096 * sizeof(float); // 4 MiB

    if (ws_size >= 8 * chunkBytes) {
        // uneven-9: L1 chunks 0..7 (2048 blocks = 2 exact resident waves),
        // L2 chunks 1..8 (2048 blocks, 224 steps except c8=256).
        hipLaunchKernelGGL((linoss_k<224, 0>), dim3(2048), dim3(256), 0, stream,
                           q, k, v, bt, ow, od, out, ws);
        hipLaunchKernelGGL((linoss_k<224, 1>), dim3(2048), dim3(256), 0, stream,
                           q, k, v, bt, ow, od, out, ws);
    } else if (ws_size >= 7 * chunkBytes) {
        // even-8 (R16-proven): L1 chunks 0..6, L2 chunks 1..7.
        hipLaunchKernelGGL((linoss_k<256, 0>), dim3(1792), dim3(256), 0, stream,
                           q, k, v, bt, ow, od, out, ws);
        hipLaunchKernelGGL((linoss_k<256, 1>), dim3(1792), dim3(256), 0, stream,
                           q, k, v, bt, ow, od, out, ws);
    } else {
        hipLaunchKernelGGL(linoss_full, dim3(256), dim3(256), 0, stream,
                           q, k, v, bt, ow, od, out);
    }
}

// Round 19
// 263.355 us; speedup vs baseline: 1.0105x; 1.0105x over previous
//
#include <hip/hip_runtime.h>

// LinOSS: damped-oscillator linear SSM scan. B=8, T=2048, H=16, D=64.
//   s = 1-sigmoid(osc_damp); a = DT*exp(osc_w)
//   z' = s*z - a*y + w,  w = DT*beta*k[d]*v[e];  y' = y + DT*z'
//   out = (1/8) q . y
//
// R16 structure (264.6us): L1 chunks 0..6 (c0 direct+dot, else eigen), all
// store ws; L2 chunks 1..7 prefix+direct+dot. R18's uneven-9 failed (256-step
// tail blocks pin both phases). R19: packed dual-f32 via ext_vector_type(2)
// + __builtin_elementwise_fma -- compiler owns selection (v_pk_fma_f32) and
// scheduling, unlike R9's asm (which broke LDS vectorization). Loads stay
// float4/b128; v2f pairs are register views. ws quad layout {y0,y1,z0,z1}
// so packed pairs move without shuffles.

constexpr float DTc = 0.01f;
constexpr int Tn = 2048, Hn = 16, Dn = 64;
constexpr int TS = Hn * Dn; // 1024 floats per t-step in q/k/v/out
constexpr int TILE = 16;

typedef float v2f __attribute__((ext_vector_type(2)));

__device__ __forceinline__ v2f vfma(v2f a, v2f b, v2f c) {
    return __builtin_elementwise_fma(a, b, c);
}

typedef const __attribute__((address_space(1))) void* as1_cvp;
typedef __attribute__((address_space(3))) void* as3_vp;

__device__ __forceinline__ void gload_lds4(const float* g, float* lds) {
    __builtin_amdgcn_global_load_lds((as1_cvp)g, (as3_vp)lds, 4, 0, 0);
}
__device__ __forceinline__ void gload_lds16(const float* g, float* lds) {
    __builtin_amdgcn_global_load_lds((as1_cvp)g, (as3_vp)lds, 16, 0, 0);
}

template<int CTRL>
__device__ __forceinline__ float dpp_add(float x) {
    int yi = __builtin_amdgcn_update_dpp(0, __float_as_int(x), CTRL, 0xF, 0xF, true);
    return x + __int_as_float(yi);
}

// MODE 0 (L1): c = blk>>8 in [0, NC-2]; c==0 direct+dot, c>0 eigen; store ws.
// MODE 1 (L2): c = c0 + (blk>>8); prefix-combine; direct+dot; no ws store.
template<int NC, int MODE>
__global__ __launch_bounds__(256, 4)
void linoss_k(const float* __restrict__ Q, const float* __restrict__ K,
              const float* __restrict__ V, const float* __restrict__ Bt,
              const float* __restrict__ OW, const float* __restrict__ OD,
              float* __restrict__ Out, float* __restrict__ WS, int c0) {
    constexpr int L = Tn / NC;

    __shared__ float sK[2][TILE][64];
    __shared__ float sQ[2][TILE][64];
    __shared__ float sV[2][TILE][32];
    __shared__ float sB[2][TILE];

    int blk = blockIdx.x;
    int c = (MODE == 0) ? (blk >> 8) : (c0 + (blk >> 8));
    bool doQ = (MODE == 1) || (c == 0);
    int sl = blk & 255;
    // XCD-aware decode: both e-halves of the same (b,h) on one XCD.
    int xcd = sl & 7, slot = sl >> 3;
    int ec = slot & 1;
    int bh = ((slot >> 1) << 3) | xcd;
    int b = bh >> 4, h = bh & 15;

    int tid = threadIdx.x;
    int dgrp = tid & 7;
    int el = tid >> 3;
    int e = ec * 32 + el;
    int d0 = dgrp * 8;
    int wv = tid >> 6;
    int ln = tid & 63;

    v2f y2[4], z2[4];
#pragma unroll
    for (int j = 0; j < 4; ++j) { y2[j] = (v2f)0.0f; z2[j] = (v2f)0.0f; }

    // per-(c,bh,ec) ws tile; quad j layout: {y[2j], y[2j+1], z[2j], z[2j+1]}
    auto wsBase = [&](int ci) {
        return WS + (((size_t)ci * 128 + bh) * 2 + ec) * 4096 + (size_t)tid * 16;
    };

    size_t bhOff = (size_t)b * Tn * TS + (size_t)h * Dn;
    const float* kb0 = K + bhOff;
    const float* qb0 = Q + bhOff;
    const float* vb0 = V + bhOff + ec * 32;
    const float* bb0 = Bt + (size_t)b * Tn * Hn + h;
    float* op = Out + bhOff + e;
    bool wlane = (dgrp == 0);

    int t0 = c * L;

    auto stage = [&](int buf, int tt0) {
        {
            int row = 4 * wv + (ln >> 4);
            gload_lds16(kb0 + (size_t)(tt0 + row) * TS + (ln & 15) * 4, &sK[buf][4 * wv][0]);
        }
        if (doQ) {
            int row = 4 * wv + (ln >> 4);
            gload_lds16(qb0 + (size_t)(tt0 + row) * TS + (ln & 15) * 4, &sQ[buf][4 * wv][0]);
        }
        if (wv < 2) {
            int row = 8 * wv + (ln >> 3);
            gload_lds16(vb0 + (size_t)(tt0 + row) * TS + (ln & 7) * 4, &sV[buf][8 * wv][0]);
        }
        if (wv == 2 && ln < 16)
            gload_lds4(bb0 + (size_t)(tt0 + ln) * Hn, &sB[buf][0]);
    };

    constexpr int nT = L / TILE;

    if (MODE == 0 && c > 0) {
        // ---------------- eigen state-only sweep (packed) ----------------
        v2f l12[4], l22[4], mt1[4], mt2[4];
        float l1s[8];
#pragma unroll
        for (int j = 0; j < 4; ++j) {
#pragma unroll
            for (int hlf = 0; hlf < 2; ++hlf) {
                int jj = 2 * j + hlf;
                int idx = (h * Dn + d0 + jj) * Dn + e;
                float aDT = DTc * expf(OW[idx]);
                float s = 1.0f - 1.0f / (1.0f + expf(-OD[idx]));
                float a00 = 1.0f - DTc * aDT, a11 = s;
                float a01 = DTc * s, a10 = -aDT;
                float tr = a00 + a11;
                float dmm = a00 - a11;
                float disc = fmaf(dmm, dmm, 4.0f * a01 * a10);
                float l1 = 0.5f * (tr + sqrtf(disc));
                l1s[jj] = l1;
                l12[j][hlf] = l1;
                l22[j][hlf] = s / l1;   // det = s exactly
            }
            mt1[j] = (v2f)0.0f; mt2[j] = (v2f)0.0f;
        }

        stage(0, t0);
        __syncthreads();
        for (int ti = 0; ti < nT; ++ti) {
            int cur = ti & 1;
            if (ti + 1 < nT) stage(cur ^ 1, t0 + (ti + 1) * TILE);
#pragma unroll 8
            for (int s = 0; s < TILE; ++s) {
                const float4* kr = (const float4*)&sK[cur][s][d0];
                float4 ka = kr[0], kb = kr[1];
                float vv = sV[cur][s][el];
                float bb = sB[cur][s];
                float bv = (DTc * bb) * vv;
                v2f bv2 = {bv, bv};
                v2f kk[4] = {{ka.x, ka.y}, {ka.z, ka.w}, {kb.x, kb.y}, {kb.z, kb.w}};
#pragma unroll
                for (int j = 0; j < 4; ++j) {
                    v2f w = bv2 * kk[j];
                    mt1[j] = vfma(l12[j], mt1[j], w);
                    mt2[j] = vfma(l22[j], mt2[j], w);
                }
            }
            __syncthreads();
        }

        // back-transform to (y,z), packed result
#pragma unroll
        for (int j = 0; j < 4; ++j) {
#pragma unroll
            for (int hlf = 0; hlf < 2; ++hlf) {
                int jj = 2 * j + hlf;
                int idx = (h * Dn + d0 + jj) * Dn + e;
                float aDT = DTc * expf(OW[idx]);
                float s = 1.0f - 1.0f / (1.0f + expf(-OD[idx]));
                float a00 = 1.0f - DTc * aDT, a11 = s;
                float a01 = DTc * s, a10 = -aDT;
                float l1 = l1s[jj], l2 = s / l1;
                float b1 = a01 / (l1 - a11);
                float b2 = (l2 - a00) / a10;
                float c1 = DTc + b1, c2 = DTc + b2;
                float rdb = 1.0f / (b2 - b1);
                float Y1 = b2 * c1 * rdb, Y2 = -b1 * c2 * rdb;
                float Z1 = -c1 * rdb, Z2 = c2 * rdb;
                float m1 = mt1[j][hlf], m2 = mt2[j][hlf];
                y2[j][hlf] = fmaf(Y1, m1, Y2 * m2);
                z2[j][hlf] = fmaf(Z1, m1, Z2 * m2);
            }
        }
    } else {
        // ---------------- direct sweep with dot (packed) ----------------
        v2f nA2[4], omc2[4];
#pragma unroll
        for (int j = 0; j < 4; ++j) {
#pragma unroll
            for (int hlf = 0; hlf < 2; ++hlf) {
                int jj = 2 * j + hlf;
                int idx = (h * Dn + d0 + jj) * Dn + e;
                nA2[j][hlf] = -DTc * expf(OW[idx]);
                omc2[j][hlf] = 1.0f - 1.0f / (1.0f + expf(-OD[idx]));
            }
        }
        const v2f dt2 = {DTc, DTc};

        if (MODE == 1 && c > 0) {
            // A = [[1+DT*nA, DT*omc],[nA, omc]]; A^L by packed squaring.
            v2f m00[4], m01[4], m10[4], m11[4];
#pragma unroll
            for (int j = 0; j < 4; ++j) {
                m00[j] = vfma(dt2, nA2[j], (v2f)1.0f);
                m01[j] = dt2 * omc2[j];
                m10[j] = nA2[j];
                m11[j] = omc2[j];
            }
            for (int pw = 1; pw < L; pw <<= 1) {
#pragma unroll
                for (int j = 0; j < 4; ++j) {
                    v2f n00 = vfma(m00[j], m00[j], m01[j] * m10[j]);
                    v2f n01 = vfma(m00[j], m01[j], m01[j] * m11[j]);
                    v2f n10 = vfma(m10[j], m00[j], m11[j] * m10[j]);
                    v2f n11 = vfma(m10[j], m01[j], m11[j] * m11[j]);
                    m00[j] = n00; m01[j] = n01; m10[j] = n10; m11[j] = n11;
                }
            }
            for (int i = 0; i < c; ++i) {
                const float4* cw = (const float4*)wsBase(i);
#pragma unroll
                for (int j = 0; j < 4; ++j) {
                    float4 w = cw[j];
                    v2f cy = {w.x, w.y};
                    v2f cz = {w.z, w.w};
                    v2f ny = vfma(m00[j], y2[j], vfma(m01[j], z2[j], cy));
                    v2f nz = vfma(m10[j], y2[j], vfma(m11[j], z2[j], cz));
                    y2[j] = ny; z2[j] = nz;
                }
            }
        }

        stage(0, t0);
        __syncthreads();
        for (int ti = 0; ti < nT; ++ti) {
            int cur = ti & 1;
            if (ti + 1 < nT) stage(cur ^ 1, t0 + (ti + 1) * TILE);
            float* ops = op + (size_t)(t0 + ti * TILE) * TS;
#pragma unroll 8
            for (int s = 0; s < TILE; ++s) {
                const float4* kr = (const float4*)&sK[cur][s][d0];
                float4 ka = kr[0], kb = kr[1];
                float vv = sV[cur][s][el];
                float bb = sB[cur][s];
                float bv = (DTc * bb) * vv;
                v2f bv2 = {bv, bv};
                v2f kk[4] = {{ka.x, ka.y}, {ka.z, ka.w}, {kb.x, kb.y}, {kb.z, kb.w}};
#pragma unroll
                for (int j = 0; j < 4; ++j) {
                    z2[j] = vfma(omc2[j], z2[j], vfma(nA2[j], y2[j], bv2 * kk[j]));
                    y2[j] = vfma(dt2, z2[j], y2[j]);
                }
                if (doQ) {
                    const float4* qr = (const float4*)&sQ[cur][s][d0];
                    float4 qa = qr[0], qb = qr[1];
                    v2f qq[4] = {{qa.x, qa.y}, {qa.z, qa.w}, {qb.x, qb.y}, {qb.z, qb.w}};
                    v2f pp = (v2f)0.0f;
#pragma unroll
                    for (int j = 0; j < 4; ++j) pp = vfma(qq[j], y2[j], pp);
                    float p = pp[0] + pp[1];
                    p = dpp_add<0xB1>(p);   // quad_perm xor1 (exact)
                    p = dpp_add<0x4E>(p);   // quad_perm xor2 (exact)
                    p += __shfl_xor(p, 4);  // cross-quad (proven)
                    if (wlane) *ops = p * 0.125f; // scale = D^-0.5
                    ops += TS;
                }
            }
            __syncthreads();
        }
    }

    if (MODE == 0) {
        float4* cw = (float4*)wsBase(c);
#pragma unroll
        for (int j = 0; j < 4; ++j) {
            float4 w;
            w.x = y2[j][0]; w.y = y2[j][1];
            w.z = z2[j][0]; w.w = z2[j][1];
            cw[j] = w;
        }
    }
}

extern "C" void kernel_launch(void* const* d_in, const int* in_sizes, int n_in,
                              void* d_out, int out_size, void* d_ws, size_t ws_size,
                              hipStream_t stream) {
    const float* q  = (const float*)d_in[0];
    const float* k  = (const float*)d_in[1];
    const float* v  = (const float*)d_in[2];
    const float* bt = (const float*)d_in[3];
    const float* ow = (const float*)d_in[4];
    const float* od = (const float*)d_in[5];
    float* out = (float*)d_out;
    float* ws = (float*)d_ws;

    const size_t chunkBytes = (size_t)128 * 2 * 4096 * sizeof(float); // 4 MiB

    if (ws_size >= 7 * chunkBytes) {
        // NC=8: L1 = chunks 0..6 (c0 direct+dot, 1..6 eigen); L2 = chunks 1..7.
        hipLaunchKernelGGL((linoss_k<8, 0>), dim3(1792), dim3(256), 0, stream,
                           q, k, v, bt, ow, od, out, ws, 0);
        hipLaunchKernelGGL((linoss_k<8, 1>), dim3(1792), dim3(256), 0, stream,
                           q, k, v, bt, ow, od, out, ws, 1);
    } else if (ws_size >= chunkBytes) {
        // NC=2: L1 = chunk 0 (direct+dot+ws); L2 = chunk 1.
        hipLaunchKernelGGL((linoss_k<2, 0>), dim3(256), dim3(256), 0, stream,
                           q, k, v, bt, ow, od, out, ws, 0);
        hipLaunchKernelGGL((linoss_k<2, 1>), dim3(256), dim3(256), 0, stream,
                           q, k, v, bt, ow, od, out, ws, 1);
    } else {
        // NC=1: single full sweep (c0=0 -> no prefix, q-dot, no ws).
        hipLaunchKernelGGL((linoss_k<1, 1>), dim3(256), dim3(256), 0, stream,
                           q, k, v, bt, ow, od, out, ws, 0);
    }
}